// Round 4
// baseline (536.415 us; speedup 1.0000x reference)
//
#include <hip/hip_runtime.h>
#include <cstdint>
#include <cstddef>

#define N_NODES 5000
#define DIN 512
#define DOUT 16
#define KMP 3
#define NCLS 100
#define WSTRIDE 160   // u32 words per bit-row (157 used, padded)
#define NWORDS 157    // ceil(5000/32)
#define NQ 1250       // float4 groups per row
#define CAPK 160      // per-plane neighbor list capacity (deg ~64±8)
#define CAPU 320      // union list capacity (deg ~189±14)
#define NJT 313       // ceil(5000/16) j-tiles for XW part

typedef float f32x4 __attribute__((ext_vector_type(4)));

// ================= K_A: bits+union+nbr lists+dinv+udinv  (+ XW GEMM) =======
// blocks [0,5000): one block per row i (bit planes / lists / degrees).
// blocks [5000,5313): XW[k][j][o] = feat[j].W[k][:,o] for ALL 3 k per block
//   (feat tile read once, 3 accumulators; was 3 separate passes).
__global__ __launch_bounds__(256)
void kA(const float* __restrict__ adj, const float* __restrict__ feat,
        const float* __restrict__ Wg,
        uint32_t* __restrict__ planes, float* __restrict__ dinv,
        float* __restrict__ udinv,
        uint16_t* __restrict__ nbrK, int* __restrict__ cntK,
        uint16_t* __restrict__ nbrU, int* __restrict__ cntU,
        float* __restrict__ XW) {
    int bid = blockIdx.x;
    int t = threadIdx.x;

    if (bid >= N_NODES) {
        // ---------------- XW part: skinny GEMM, all 3 k's per tile ---------
        int b2 = bid - N_NODES;          // 0..312
        int j = b2 * 16 + (t >> 4);
        int o = t & 15;
        if (j < N_NODES) {
            const f32x4* f4 = (const f32x4*)(feat + (size_t)j * DIN);
            const float* w0 = Wg + (size_t)0 * DIN * DOUT + o;
            const float* w1 = Wg + (size_t)1 * DIN * DOUT + o;
            const float* w2 = Wg + (size_t)2 * DIN * DOUT + o;
            float acc0 = 0.f, acc1 = 0.f, acc2 = 0.f;
            #pragma unroll 2
            for (int d4 = 0; d4 < DIN / 4; ++d4) {
                f32x4 f = f4[d4];
                int d = 4 * d4;
                acc0 += f.x * w0[(d + 0) * DOUT] + f.y * w0[(d + 1) * DOUT]
                      + f.z * w0[(d + 2) * DOUT] + f.w * w0[(d + 3) * DOUT];
                acc1 += f.x * w1[(d + 0) * DOUT] + f.y * w1[(d + 1) * DOUT]
                      + f.z * w1[(d + 2) * DOUT] + f.w * w1[(d + 3) * DOUT];
                acc2 += f.x * w2[(d + 0) * DOUT] + f.y * w2[(d + 1) * DOUT]
                      + f.z * w2[(d + 2) * DOUT] + f.w * w2[(d + 3) * DOUT];
            }
            XW[((size_t)0 * N_NODES + j) * DOUT + o] = acc0;
            XW[((size_t)1 * N_NODES + j) * DOUT + o] = acc1;
            XW[((size_t)2 * N_NODES + j) * DOUT + o] = acc2;
        }
        return;
    }

    int i = bid;
    int lane = t & 63;
    int wv   = t >> 6;
    __shared__ uint32_t nib32[KMP][320];   // 3 x 1280 nibble bytes
    __shared__ int wtot[4][4];             // [scan id][wave]

    // ---- load burst: 15 independent float4 loads/thread (nontemporal) ----
    #pragma unroll
    for (int it = 0; it < 15; ++it) {
        const int k  = it / 5;                  // constant per unrolled iter
        const int ql = (it - 5 * k) * 256 + t;  // 0..1279
        uint32_t m = 0;
        if (ql < NQ) {
            const f32x4* arow4 = (const f32x4*)(adj + ((size_t)k * N_NODES + i) * N_NODES);
            f32x4 v = __builtin_nontemporal_load(arow4 + ql);
            m = (v.x != 0.f ? 1u : 0u) | (v.y != 0.f ? 2u : 0u) |
                (v.z != 0.f ? 4u : 0u) | (v.w != 0.f ? 8u : 0u);
        }
        ((uint8_t*)nib32[k])[ql] = (uint8_t)m;
    }
    __syncthreads();

    // ---- pack 3 words + union ----
    uint32_t w[4];
    int cnt[4];
    #pragma unroll
    for (int k = 0; k < KMP; ++k) {
        uint32_t word = 0;
        if (t < NWORDS) {
            uint32_t lo = nib32[k][2 * t], hi = nib32[k][2 * t + 1];
            word = (lo & 0xFu) | ((lo >> 4) & 0xF0u) | ((lo >> 8) & 0xF00u) | ((lo >> 12) & 0xF000u)
                 | ((hi << 16) & 0xF0000u) | ((hi << 12) & 0xF00000u)
                 | ((hi << 8) & 0xF000000u) | ((hi << 4) & 0xF0000000u);
            planes[((size_t)k * N_NODES + i) * WSTRIDE + t] = word;
        }
        w[k] = word;
        cnt[k] = __popc(word);
    }
    w[3] = w[0] | w[1] | w[2];
    cnt[3] = __popc(w[3]);

    // ---- 4 simultaneous block scans ----
    int x[4];
    #pragma unroll
    for (int q = 0; q < 4; ++q) x[q] = cnt[q];
    #pragma unroll
    for (int s = 1; s < 64; s <<= 1) {
        int y0 = __shfl_up(x[0], s), y1 = __shfl_up(x[1], s);
        int y2 = __shfl_up(x[2], s), y3 = __shfl_up(x[3], s);
        if (lane >= s) { x[0] += y0; x[1] += y1; x[2] += y2; x[3] += y3; }
    }
    if (lane == 63) {
        wtot[0][wv] = x[0]; wtot[1][wv] = x[1];
        wtot[2][wv] = x[2]; wtot[3][wv] = x[3];
    }
    __syncthreads();

    // ---- extraction ----
    #pragma unroll
    for (int q = 0; q < 4; ++q) {
        int prefix = 0, total = 0;
        #pragma unroll
        for (int wq = 0; wq < 4; ++wq) {
            int v = wtot[q][wq];
            total += v;
            if (wq < wv) prefix += v;
        }
        int pos = prefix + x[q] - cnt[q];
        uint32_t word = w[q];
        if (q < KMP) {
            uint16_t* out = nbrK + ((size_t)q * N_NODES + i) * CAPK;
            while (word) {
                int b = __builtin_ctz(word);
                word &= word - 1;
                if (pos < CAPK) out[pos] = (uint16_t)(32 * t + b);
                ++pos;
            }
            if (t == 0) {
                dinv[q * N_NODES + i] = rsqrtf(1.0f + (float)total);
                cntK[q * N_NODES + i] = (total < CAPK) ? total : CAPK;
            }
        } else {
            uint16_t* out = nbrU + (size_t)i * CAPU;
            while (word) {
                int b = __builtin_ctz(word);
                word &= word - 1;
                if (pos < CAPU) out[pos] = (uint16_t)(32 * t + b);
                ++pos;
            }
            if (t == 0) {
                cntU[i] = (total < CAPU) ? total : CAPU;
                udinv[i] = rsqrtf(1.0f + (float)total);
            }
        }
    }
}

// ---- K34: sparse h + max -> f_meta, attention coeffs a4/b4, and Gd --------
// Block per row i, 192 threads = 3 waves, wave k handles meta-path k.
// Per-wave chain is 1/3 of the round-3 version; 3x the concurrent waves.
__global__ __launch_bounds__(192)
void k34_fmeta_ab_gd(const uint16_t* __restrict__ nbrK, const int* __restrict__ cntK,
                     const float* __restrict__ XW, const float* __restrict__ dinv,
                     const float* __restrict__ bg, const float* __restrict__ aw,
                     const float* __restrict__ Wf, const float* __restrict__ udinv,
                     float* __restrict__ f_meta, float* __restrict__ a4,
                     float* __restrict__ b4, float* __restrict__ Gd) {
    int i = blockIdx.x;
    int t = threadIdx.x;
    int k = t >> 6;                 // wave id = meta-path
    int lane = t & 63;
    int o = lane & 15;
    int s = lane >> 4;              // neighbor slice 0..3
    __shared__ float hs[KMP][16];
    __shared__ float fm[16];

    const float* xw = XW + (size_t)k * N_NODES * DOUT;
    const float* dv = dinv + (size_t)k * N_NODES;
    int row = k * N_NODES + i;
    int nn = cntK[row];
    const uint16_t* nb = nbrK + (size_t)row * CAPK;
    float di = dv[i];
    float a0 = 0.f, a1 = 0.f, a2 = 0.f, a3 = 0.f;
    for (int n0 = 4 * s; n0 < nn; n0 += 16) {
        ushort4 jj = *(const ushort4*)(nb + n0);      // 8B aligned, within CAPK
        a0 += dv[jj.x] * xw[(int)jj.x * DOUT + o];    // n0 < nn guaranteed
        if (n0 + 1 < nn) a1 += dv[jj.y] * xw[(int)jj.y * DOUT + o];
        if (n0 + 2 < nn) a2 += dv[jj.z] * xw[(int)jj.z * DOUT + o];
        if (n0 + 3 < nn) a3 += dv[jj.w] * xw[(int)jj.w * DOUT + o];
    }
    float red = (a0 + a1) + (a2 + a3);
    red += __shfl_xor(red, 16);
    red += __shfl_xor(red, 32);
    red += di * xw[i * DOUT + o];                     // self-loop
    float h = di * red + bg[k * DOUT + o];
    if (s == 0) hs[k][o] = h;
    __syncthreads();

    // wave 0: hmax over k, f_meta, attention coefficients
    if (k == 0) {
        float hm = fmaxf(fmaxf(hs[0][o], hs[1][o]), hs[2][o]);
        if (s == 0) { f_meta[i * DOUT + o] = hm; fm[o] = hm; }
        float sa0 = hm * aw[0 * 32 + o], sb0 = hm * aw[0 * 32 + 16 + o];
        float sa1 = hm * aw[1 * 32 + o], sb1 = hm * aw[1 * 32 + 16 + o];
        float sa2 = hm * aw[2 * 32 + o], sb2 = hm * aw[2 * 32 + 16 + o];
        #pragma unroll
        for (int sh = 1; sh < 16; sh <<= 1) {
            sa0 += __shfl_xor(sa0, sh, 16); sb0 += __shfl_xor(sb0, sh, 16);
            sa1 += __shfl_xor(sa1, sh, 16); sb1 += __shfl_xor(sb1, sh, 16);
            sa2 += __shfl_xor(sa2, sh, 16); sb2 += __shfl_xor(sb2, sh, 16);
        }
        if (s == 0 && o < 4) {
            float sa = (o == 0) ? sa0 : (o == 1) ? sa1 : (o == 2) ? sa2 : 0.f;
            float sb = (o == 0) ? sb0 : (o == 1) ? sb1 : (o == 2) ? sb2 : 0.f;
            a4[i * 4 + o] = sa;
            b4[i * 4 + o] = sb;
        }
    }
    __syncthreads();

    // Gd[i][c] = udinv[i] * (f_meta[i] . W_final[:,c])
    if (t < NCLS) {
        float ud = udinv[i];
        float acc = 0.f;
        #pragma unroll
        for (int q = 0; q < DOUT; ++q) acc += fm[q] * Wf[q * NCLS + t];
        Gd[(size_t)i * NCLS + t] = acc * ud;
    }
}

// ------- K_C: k5 (dense A_meta) + k8 (pred SpMM) merged via block split ----
__device__ __forceinline__ float attn_frac(float x0, float x1, float x2,
                                           uint32_t b0, uint32_t b1, uint32_t b2) {
    float e0 = __expf(fmaxf(x0, 0.f));
    float e1 = __expf(fmaxf(x1, 0.f));
    float e2 = __expf(fmaxf(x2, 0.f));
    float num = (b0 ? e0 : 0.f) + (b1 ? e1 : 0.f) + (b2 ? e2 : 0.f);
    return __fdividef(num, e0 + e1 + e2);
}

#define NB_K5 1250   // 5000/4 rows-of-4 blocks (was 8 rows: more waves now)

__global__ __launch_bounds__(256)
void kC(const uint32_t* __restrict__ planes,
        const float* __restrict__ a4, const float* __restrict__ b4,
        float* __restrict__ Am,
        const uint16_t* __restrict__ nbrU, const int* __restrict__ cntU,
        const float* __restrict__ Gd, const float* __restrict__ udinv,
        const float* __restrict__ bf, float* __restrict__ pred) {
    int bid = blockIdx.x;
    int t = threadIdx.x;

    if (bid < NB_K5) {
        // ----------------- k5: dense A_meta, softmax over k ----------------
        int i0 = bid * 4;
        __shared__ float a_s[4][3];
        if (t < 12) { int r = t / 3, k = t % 3; a_s[r][k] = a4[(i0 + r) * 4 + k]; }
        __syncthreads();
        for (int c = 0; c < 5; ++c) {
            int j4 = 4 * (t + 256 * c);
            if (j4 >= N_NODES) break;
            int w = j4 >> 5, sh = j4 & 31;
            const float4* bp = (const float4*)(b4 + (size_t)j4 * 4);
            float4 bj0 = bp[0], bj1 = bp[1], bj2 = bp[2], bj3 = bp[3];
            #pragma unroll
            for (int r = 0; r < 4; ++r) {
                int i = i0 + r;
                uint32_t q0 = planes[(size_t)i * WSTRIDE + w] >> sh;
                uint32_t q1 = planes[(size_t)(N_NODES + i) * WSTRIDE + w] >> sh;
                uint32_t q2 = planes[(size_t)(2 * N_NODES + i) * WSTRIDE + w] >> sh;
                uint32_t un = (q0 | q1 | q2) & 0xFu;
                f32x4 outv = (f32x4)(0.f);
                if (un) {
                    float A0 = a_s[r][0], A1 = a_s[r][1], A2 = a_s[r][2];
                    if (un & 1u) outv.x = attn_frac(A0 + bj0.x, A1 + bj0.y, A2 + bj0.z, q0 & 1u, q1 & 1u, q2 & 1u);
                    if (un & 2u) outv.y = attn_frac(A0 + bj1.x, A1 + bj1.y, A2 + bj1.z, q0 & 2u, q1 & 2u, q2 & 2u);
                    if (un & 4u) outv.z = attn_frac(A0 + bj2.x, A1 + bj2.y, A2 + bj2.z, q0 & 4u, q1 & 4u, q2 & 4u);
                    if (un & 8u) outv.w = attn_frac(A0 + bj3.x, A1 + bj3.y, A2 + bj3.z, q0 & 8u, q1 & 8u, q2 & 8u);
                }
                __builtin_nontemporal_store(outv, (f32x4*)(Am + (size_t)i * N_NODES + j4));
            }
        }
    } else {
        // ----------------- k8: predictions SpMM over union list ------------
        int b2 = bid - NB_K5;           // 0..2499
        int i = b2 * 2 + (t >> 7);      // 2 rows per block
        int c = t & 127;
        if (c >= NCLS) return;
        int nn = cntU[i];
        const uint16_t* nb = nbrU + (size_t)i * CAPU;
        float a0 = Gd[(size_t)i * NCLS + c];  // self-loop
        float a1 = 0.f, a2 = 0.f, a3 = 0.f;
        int n = 0;
        for (; n + 4 <= nn; n += 4) {
            ushort4 jj = *(const ushort4*)(nb + n);
            a0 += Gd[(size_t)jj.x * NCLS + c];
            a1 += Gd[(size_t)jj.y * NCLS + c];
            a2 += Gd[(size_t)jj.z * NCLS + c];
            a3 += Gd[(size_t)jj.w * NCLS + c];
        }
        for (; n < nn; ++n) a0 += Gd[(size_t)nb[n] * NCLS + c];
        pred[(size_t)i * NCLS + c] = udinv[i] * ((a0 + a1) + (a2 + a3)) + bf[c];
    }
}

extern "C" void kernel_launch(void* const* d_in, const int* in_sizes, int n_in,
                              void* d_out, int out_size, void* d_ws, size_t ws_size,
                              hipStream_t stream) {
    const float* feat = (const float*)d_in[0];
    const float* adj  = (const float*)d_in[1];
    const float* Wg   = (const float*)d_in[2];
    const float* bg   = (const float*)d_in[3];
    const float* aw   = (const float*)d_in[4];
    const float* Wf   = (const float*)d_in[5];
    const float* bf   = (const float*)d_in[6];

    float* f_meta = (float*)d_out;
    float* Am     = f_meta + (size_t)N_NODES * DOUT;
    float* pred   = Am + (size_t)N_NODES * N_NODES;

    char* ws = (char*)d_ws;
    size_t off = 0;
    auto alloc = [&](size_t bytes) {
        void* p = ws + off;
        off = (off + bytes + 255) & ~(size_t)255;
        return p;
    };
    uint32_t* planes = (uint32_t*)alloc((size_t)KMP * N_NODES * WSTRIDE * 4);
    float* dinv  = (float*)alloc((size_t)KMP * N_NODES * 4);
    float* XW    = (float*)alloc((size_t)KMP * N_NODES * DOUT * 4);
    float* a4    = (float*)alloc((size_t)N_NODES * 16);
    float* b4    = (float*)alloc((size_t)N_NODES * 16);
    float* udinv = (float*)alloc((size_t)N_NODES * 4);
    float* Gd    = (float*)alloc((size_t)N_NODES * NCLS * 4);
    uint16_t* nbrK = (uint16_t*)alloc((size_t)KMP * N_NODES * CAPK * 2);
    int*      cntK = (int*)alloc((size_t)KMP * N_NODES * 4);
    uint16_t* nbrU = (uint16_t*)alloc((size_t)N_NODES * CAPU * 2);
    int*      cntU = (int*)alloc((size_t)N_NODES * 4);

    hipLaunchKernelGGL(kA, dim3(N_NODES + NJT), dim3(256), 0, stream,
                       adj, feat, Wg, planes, dinv, udinv, nbrK, cntK, nbrU, cntU, XW);
    hipLaunchKernelGGL(k34_fmeta_ab_gd, dim3(N_NODES), dim3(192), 0, stream,
                       nbrK, cntK, XW, dinv, bg, aw, Wf, udinv, f_meta, a4, b4, Gd);
    hipLaunchKernelGGL(kC, dim3(NB_K5 + N_NODES / 2), dim3(256), 0, stream,
                       planes, a4, b4, Am, nbrU, cntU, Gd, udinv, bf, pred);
}

// Round 5
// 530.693 us; speedup vs baseline: 1.0108x; 1.0108x over previous
//
#include <hip/hip_runtime.h>
#include <cstdint>
#include <cstddef>

#define N_NODES 5000
#define DIN 512
#define DOUT 16
#define KMP 3
#define NCLS 100
#define WSTRIDE 160   // u32 words per bit-row (157 used, padded)
#define NWORDS 157    // ceil(5000/32)
#define NQ 1250       // float4 groups per row
#define CAPK 160      // per-plane neighbor list capacity (deg ~64±8)
#define CAPU 320      // union list capacity (deg ~189±14)
#define NJT 313       // ceil(5000/16) j-tiles for XW part

typedef float f32x4 __attribute__((ext_vector_type(4)));

// ================= K_A: bits+union+nbr lists+dinv+udinv  (+ XW GEMM) =======
// blocks [0,5000): one block per row i (bit planes / lists / degrees).
// blocks [5000,5313): XW[k][j][o] = feat[j].W[k][:,o] for ALL 3 k per block.
__global__ __launch_bounds__(256)
void kA(const float* __restrict__ adj, const float* __restrict__ feat,
        const float* __restrict__ Wg,
        uint32_t* __restrict__ planes, float* __restrict__ dinv,
        float* __restrict__ udinv,
        uint16_t* __restrict__ nbrK, int* __restrict__ cntK,
        uint16_t* __restrict__ nbrU, int* __restrict__ cntU,
        float* __restrict__ XW) {
    int bid = blockIdx.x;
    int t = threadIdx.x;

    if (bid >= N_NODES) {
        // ---------------- XW part: skinny GEMM, all 3 k's per tile ---------
        int b2 = bid - N_NODES;          // 0..312
        int j = b2 * 16 + (t >> 4);
        int o = t & 15;
        if (j < N_NODES) {
            const f32x4* f4 = (const f32x4*)(feat + (size_t)j * DIN);
            const float* w0 = Wg + (size_t)0 * DIN * DOUT + o;
            const float* w1 = Wg + (size_t)1 * DIN * DOUT + o;
            const float* w2 = Wg + (size_t)2 * DIN * DOUT + o;
            float acc0 = 0.f, acc1 = 0.f, acc2 = 0.f;
            #pragma unroll 2
            for (int d4 = 0; d4 < DIN / 4; ++d4) {
                f32x4 f = f4[d4];
                int d = 4 * d4;
                acc0 += f.x * w0[(d + 0) * DOUT] + f.y * w0[(d + 1) * DOUT]
                      + f.z * w0[(d + 2) * DOUT] + f.w * w0[(d + 3) * DOUT];
                acc1 += f.x * w1[(d + 0) * DOUT] + f.y * w1[(d + 1) * DOUT]
                      + f.z * w1[(d + 2) * DOUT] + f.w * w1[(d + 3) * DOUT];
                acc2 += f.x * w2[(d + 0) * DOUT] + f.y * w2[(d + 1) * DOUT]
                      + f.z * w2[(d + 2) * DOUT] + f.w * w2[(d + 3) * DOUT];
            }
            XW[((size_t)0 * N_NODES + j) * DOUT + o] = acc0;
            XW[((size_t)1 * N_NODES + j) * DOUT + o] = acc1;
            XW[((size_t)2 * N_NODES + j) * DOUT + o] = acc2;
        }
        return;
    }

    int i = bid;
    int lane = t & 63;
    int wv   = t >> 6;
    __shared__ uint32_t nib32[KMP][320];   // 3 x 1280 nibble bytes
    __shared__ int wtot[4][4];             // [scan id][wave]

    // ---- load burst: 15 independent float4 loads/thread (nontemporal) ----
    #pragma unroll
    for (int it = 0; it < 15; ++it) {
        const int k  = it / 5;                  // constant per unrolled iter
        const int ql = (it - 5 * k) * 256 + t;  // 0..1279
        uint32_t m = 0;
        if (ql < NQ) {
            const f32x4* arow4 = (const f32x4*)(adj + ((size_t)k * N_NODES + i) * N_NODES);
            f32x4 v = __builtin_nontemporal_load(arow4 + ql);
            m = (v.x != 0.f ? 1u : 0u) | (v.y != 0.f ? 2u : 0u) |
                (v.z != 0.f ? 4u : 0u) | (v.w != 0.f ? 8u : 0u);
        }
        ((uint8_t*)nib32[k])[ql] = (uint8_t)m;
    }
    __syncthreads();

    // ---- pack 3 words + union ----
    uint32_t w[4];
    int cnt[4];
    #pragma unroll
    for (int k = 0; k < KMP; ++k) {
        uint32_t word = 0;
        if (t < NWORDS) {
            uint32_t lo = nib32[k][2 * t], hi = nib32[k][2 * t + 1];
            word = (lo & 0xFu) | ((lo >> 4) & 0xF0u) | ((lo >> 8) & 0xF00u) | ((lo >> 12) & 0xF000u)
                 | ((hi << 16) & 0xF0000u) | ((hi << 12) & 0xF00000u)
                 | ((hi << 8) & 0xF000000u) | ((hi << 4) & 0xF0000000u);
            planes[((size_t)k * N_NODES + i) * WSTRIDE + t] = word;
        }
        w[k] = word;
        cnt[k] = __popc(word);
    }
    w[3] = w[0] | w[1] | w[2];
    cnt[3] = __popc(w[3]);

    // ---- 4 simultaneous block scans ----
    int x[4];
    #pragma unroll
    for (int q = 0; q < 4; ++q) x[q] = cnt[q];
    #pragma unroll
    for (int s = 1; s < 64; s <<= 1) {
        int y0 = __shfl_up(x[0], s), y1 = __shfl_up(x[1], s);
        int y2 = __shfl_up(x[2], s), y3 = __shfl_up(x[3], s);
        if (lane >= s) { x[0] += y0; x[1] += y1; x[2] += y2; x[3] += y3; }
    }
    if (lane == 63) {
        wtot[0][wv] = x[0]; wtot[1][wv] = x[1];
        wtot[2][wv] = x[2]; wtot[3][wv] = x[3];
    }
    __syncthreads();

    // ---- extraction ----
    #pragma unroll
    for (int q = 0; q < 4; ++q) {
        int prefix = 0, total = 0;
        #pragma unroll
        for (int wq = 0; wq < 4; ++wq) {
            int v = wtot[q][wq];
            total += v;
            if (wq < wv) prefix += v;
        }
        int pos = prefix + x[q] - cnt[q];
        uint32_t word = w[q];
        if (q < KMP) {
            uint16_t* out = nbrK + ((size_t)q * N_NODES + i) * CAPK;
            while (word) {
                int b = __builtin_ctz(word);
                word &= word - 1;
                if (pos < CAPK) out[pos] = (uint16_t)(32 * t + b);
                ++pos;
            }
            if (t == 0) {
                dinv[q * N_NODES + i] = rsqrtf(1.0f + (float)total);
                cntK[q * N_NODES + i] = (total < CAPK) ? total : CAPK;
            }
        } else {
            uint16_t* out = nbrU + (size_t)i * CAPU;
            while (word) {
                int b = __builtin_ctz(word);
                word &= word - 1;
                if (pos < CAPU) out[pos] = (uint16_t)(32 * t + b);
                ++pos;
            }
            if (t == 0) {
                cntU[i] = (total < CAPU) ? total : CAPU;
                udinv[i] = rsqrtf(1.0f + (float)total);
            }
        }
    }
}

// ---- K34: sparse h + max -> f_meta, attention coeffs a4/b4, and Gd --------
// One 64-lane wave per row: lane = (o, s) = (out-dim, neighbor slice).
__global__ __launch_bounds__(256)
void k34_fmeta_ab_gd(const uint16_t* __restrict__ nbrK, const int* __restrict__ cntK,
                     const float* __restrict__ XW, const float* __restrict__ dinv,
                     const float* __restrict__ bg, const float* __restrict__ aw,
                     const float* __restrict__ Wf, const float* __restrict__ udinv,
                     float* __restrict__ f_meta, float* __restrict__ a4,
                     float* __restrict__ b4, float* __restrict__ Gd) {
    int t = threadIdx.x;
    int wv = t >> 6;
    int lane = t & 63;
    int o = lane & 15;
    int s = lane >> 4;              // neighbor slice 0..3
    int i = blockIdx.x * 4 + wv;
    __shared__ float fs[4][17];

    float hmax = -1e30f;
    #pragma unroll
    for (int k = 0; k < KMP; ++k) {
        const float* xw = XW + (size_t)k * N_NODES * DOUT;
        const float* dv = dinv + (size_t)k * N_NODES;
        int row = k * N_NODES + i;
        int nn = cntK[row];
        const uint16_t* nb = nbrK + (size_t)row * CAPK;
        float di = dv[i];
        float a0 = 0.f, a1 = 0.f, a2 = 0.f, a3 = 0.f;
        for (int n0 = 4 * s; n0 < nn; n0 += 16) {
            ushort4 jj = *(const ushort4*)(nb + n0);      // 8B aligned, within CAPK
            a0 += dv[jj.x] * xw[(int)jj.x * DOUT + o];    // n0 < nn guaranteed
            if (n0 + 1 < nn) a1 += dv[jj.y] * xw[(int)jj.y * DOUT + o];
            if (n0 + 2 < nn) a2 += dv[jj.z] * xw[(int)jj.z * DOUT + o];
            if (n0 + 3 < nn) a3 += dv[jj.w] * xw[(int)jj.w * DOUT + o];
        }
        float red = (a0 + a1) + (a2 + a3);
        red += __shfl_xor(red, 16);
        red += __shfl_xor(red, 32);
        red += di * xw[i * DOUT + o];                     // self-loop
        float h = di * red + bg[k * DOUT + o];
        hmax = fmaxf(hmax, h);
    }
    if (s == 0) {
        f_meta[i * DOUT + o] = hmax;
        fs[wv][o] = hmax;
    }
    __syncthreads();

    // attention coefficients (16-wide o-reduction; all 4 s-groups redundant)
    float sa0 = hmax * aw[0 * 32 + o], sb0 = hmax * aw[0 * 32 + 16 + o];
    float sa1 = hmax * aw[1 * 32 + o], sb1 = hmax * aw[1 * 32 + 16 + o];
    float sa2 = hmax * aw[2 * 32 + o], sb2 = hmax * aw[2 * 32 + 16 + o];
    #pragma unroll
    for (int sh = 1; sh < 16; sh <<= 1) {
        sa0 += __shfl_xor(sa0, sh, 16); sb0 += __shfl_xor(sb0, sh, 16);
        sa1 += __shfl_xor(sa1, sh, 16); sb1 += __shfl_xor(sb1, sh, 16);
        sa2 += __shfl_xor(sa2, sh, 16); sb2 += __shfl_xor(sb2, sh, 16);
    }
    if (s == 0 && o < 4) {
        float sa = (o == 0) ? sa0 : (o == 1) ? sa1 : (o == 2) ? sa2 : 0.f;
        float sb = (o == 0) ? sb0 : (o == 1) ? sb1 : (o == 2) ? sb2 : 0.f;
        a4[i * 4 + o] = sa;
        b4[i * 4 + o] = sb;
    }

    // Gd[i][c] = udinv[i] * (f_meta[i] . W_final[:,c]); 64 lanes cover 100 c's
    float f[DOUT];
    #pragma unroll
    for (int q = 0; q < DOUT; ++q) f[q] = fs[wv][q];
    float ud = udinv[i];
    for (int c = lane; c < NCLS; c += 64) {
        float acc = 0.f;
        #pragma unroll
        for (int q = 0; q < DOUT; ++q) acc += f[q] * Wf[q * NCLS + c];
        Gd[(size_t)i * NCLS + c] = acc * ud;
    }
}

// ------- K_C: k5 (dense A_meta) + k8 (pred SpMM) merged via block split ----
__device__ __forceinline__ float attn_frac(float x0, float x1, float x2,
                                           uint32_t b0, uint32_t b1, uint32_t b2) {
    float e0 = __expf(fmaxf(x0, 0.f));
    float e1 = __expf(fmaxf(x1, 0.f));
    float e2 = __expf(fmaxf(x2, 0.f));
    float num = (b0 ? e0 : 0.f) + (b1 ? e1 : 0.f) + (b2 ? e2 : 0.f);
    return __fdividef(num, e0 + e1 + e2);
}

#define NB_K5 625   // 5000/8 rows-of-8 blocks (R3 value: fewer plane re-reads)

__global__ __launch_bounds__(256)
void kC(const uint32_t* __restrict__ planes,
        const float* __restrict__ a4, const float* __restrict__ b4,
        float* __restrict__ Am,
        const uint16_t* __restrict__ nbrU, const int* __restrict__ cntU,
        const float* __restrict__ Gd, const float* __restrict__ udinv,
        const float* __restrict__ bf, float* __restrict__ pred) {
    int bid = blockIdx.x;
    int t = threadIdx.x;

    if (bid < NB_K5) {
        // ----------------- k5: dense A_meta, softmax over k ----------------
        int i0 = bid * 8;
        __shared__ float a_s[8][3];
        if (t < 24) { int r = t / 3, k = t % 3; a_s[r][k] = a4[(i0 + r) * 4 + k]; }
        __syncthreads();
        for (int c = 0; c < 5; ++c) {
            int j4 = 4 * (t + 256 * c);
            if (j4 >= N_NODES) break;
            int w = j4 >> 5, sh = j4 & 31;
            const float4* bp = (const float4*)(b4 + (size_t)j4 * 4);
            float4 bj0 = bp[0], bj1 = bp[1], bj2 = bp[2], bj3 = bp[3];
            #pragma unroll
            for (int r = 0; r < 8; ++r) {
                int i = i0 + r;
                uint32_t q0 = planes[(size_t)i * WSTRIDE + w] >> sh;
                uint32_t q1 = planes[(size_t)(N_NODES + i) * WSTRIDE + w] >> sh;
                uint32_t q2 = planes[(size_t)(2 * N_NODES + i) * WSTRIDE + w] >> sh;
                uint32_t un = (q0 | q1 | q2) & 0xFu;
                f32x4 outv = (f32x4)(0.f);
                if (un) {
                    float A0 = a_s[r][0], A1 = a_s[r][1], A2 = a_s[r][2];
                    if (un & 1u) outv.x = attn_frac(A0 + bj0.x, A1 + bj0.y, A2 + bj0.z, q0 & 1u, q1 & 1u, q2 & 1u);
                    if (un & 2u) outv.y = attn_frac(A0 + bj1.x, A1 + bj1.y, A2 + bj1.z, q0 & 2u, q1 & 2u, q2 & 2u);
                    if (un & 4u) outv.z = attn_frac(A0 + bj2.x, A1 + bj2.y, A2 + bj2.z, q0 & 4u, q1 & 4u, q2 & 4u);
                    if (un & 8u) outv.w = attn_frac(A0 + bj3.x, A1 + bj3.y, A2 + bj3.z, q0 & 8u, q1 & 8u, q2 & 8u);
                }
                __builtin_nontemporal_store(outv, (f32x4*)(Am + (size_t)i * N_NODES + j4));
            }
        }
    } else {
        // ----------------- k8: predictions SpMM over union list (ILP8) -----
        int b2 = bid - NB_K5;           // 0..2499
        int i = b2 * 2 + (t >> 7);      // 2 rows per block
        int c = t & 127;
        if (c >= NCLS) return;
        int nn = cntU[i];
        const uint16_t* nb = nbrU + (size_t)i * CAPU;
        float a0 = Gd[(size_t)i * NCLS + c];  // self-loop
        float a1 = 0.f, a2 = 0.f, a3 = 0.f;
        float a4v = 0.f, a5 = 0.f, a6 = 0.f, a7 = 0.f;
        int n = 0;
        for (; n + 8 <= nn; n += 8) {
            ushort4 j0 = *(const ushort4*)(nb + n);
            ushort4 j1 = *(const ushort4*)(nb + n + 4);
            a0  += Gd[(size_t)j0.x * NCLS + c];
            a1  += Gd[(size_t)j0.y * NCLS + c];
            a2  += Gd[(size_t)j0.z * NCLS + c];
            a3  += Gd[(size_t)j0.w * NCLS + c];
            a4v += Gd[(size_t)j1.x * NCLS + c];
            a5  += Gd[(size_t)j1.y * NCLS + c];
            a6  += Gd[(size_t)j1.z * NCLS + c];
            a7  += Gd[(size_t)j1.w * NCLS + c];
        }
        for (; n < nn; ++n) a0 += Gd[(size_t)nb[n] * NCLS + c];
        pred[(size_t)i * NCLS + c] = udinv[i] *
            (((a0 + a1) + (a2 + a3)) + ((a4v + a5) + (a6 + a7))) + bf[c];
    }
}

extern "C" void kernel_launch(void* const* d_in, const int* in_sizes, int n_in,
                              void* d_out, int out_size, void* d_ws, size_t ws_size,
                              hipStream_t stream) {
    const float* feat = (const float*)d_in[0];
    const float* adj  = (const float*)d_in[1];
    const float* Wg   = (const float*)d_in[2];
    const float* bg   = (const float*)d_in[3];
    const float* aw   = (const float*)d_in[4];
    const float* Wf   = (const float*)d_in[5];
    const float* bf   = (const float*)d_in[6];

    float* f_meta = (float*)d_out;
    float* Am     = f_meta + (size_t)N_NODES * DOUT;
    float* pred   = Am + (size_t)N_NODES * N_NODES;

    char* ws = (char*)d_ws;
    size_t off = 0;
    auto alloc = [&](size_t bytes) {
        void* p = ws + off;
        off = (off + bytes + 255) & ~(size_t)255;
        return p;
    };
    uint32_t* planes = (uint32_t*)alloc((size_t)KMP * N_NODES * WSTRIDE * 4);
    float* dinv  = (float*)alloc((size_t)KMP * N_NODES * 4);
    float* XW    = (float*)alloc((size_t)KMP * N_NODES * DOUT * 4);
    float* a4    = (float*)alloc((size_t)N_NODES * 16);
    float* b4    = (float*)alloc((size_t)N_NODES * 16);
    float* udinv = (float*)alloc((size_t)N_NODES * 4);
    float* Gd    = (float*)alloc((size_t)N_NODES * NCLS * 4);
    uint16_t* nbrK = (uint16_t*)alloc((size_t)KMP * N_NODES * CAPK * 2);
    int*      cntK = (int*)alloc((size_t)KMP * N_NODES * 4);
    uint16_t* nbrU = (uint16_t*)alloc((size_t)N_NODES * CAPU * 2);
    int*      cntU = (int*)alloc((size_t)N_NODES * 4);

    hipLaunchKernelGGL(kA, dim3(N_NODES + NJT), dim3(256), 0, stream,
                       adj, feat, Wg, planes, dinv, udinv, nbrK, cntK, nbrU, cntU, XW);
    hipLaunchKernelGGL(k34_fmeta_ab_gd, dim3(N_NODES / 4), dim3(256), 0, stream,
                       nbrK, cntK, XW, dinv, bg, aw, Wf, udinv, f_meta, a4, b4, Gd);
    hipLaunchKernelGGL(kC, dim3(NB_K5 + N_NODES / 2), dim3(256), 0, stream,
                       planes, a4, b4, Am, nbrU, cntU, Gd, udinv, bf, pred);
}